// Round 14
// baseline (586.302 us; speedup 1.0000x reference)
//
#include <hip/hip_runtime.h>
#include <stdint.h>

#define DEV __device__ __forceinline__

using bf16x8 = __attribute__((ext_vector_type(8))) __bf16;
using f32x4  = __attribute__((ext_vector_type(4))) float;

static constexpr int D    = 1024;
static constexpr int V    = 50257;
static constexpr int DFF  = 2048;
static constexpr int KD   = 3;     // depth
static constexpr int MR   = 512;   // padded rows per depth: r = b*256 + p
static constexpr int PLEN = 253;
static constexpr int CVTB = 128;   // side-band cvt blocks per trunk GEMM dispatch

DEV unsigned short f2b(float f) {
  unsigned int u = __float_as_uint(f);
  u += 0x7fffu + ((u >> 16) & 1u);   // RNE
  return (unsigned short)(u >> 16);
}

DEV void gload16(const void* g, void* l) {
  __builtin_amdgcn_global_load_lds(
      (const __attribute__((address_space(1))) unsigned int*)g,
      (__attribute__((address_space(3))) unsigned int*)l, 16, 0, 0);
}

// ---------- 6-slice f32 -> bf16 convert (grid-y picks slice) ----------
__global__ void cvt_all(
    const float* s0, unsigned short* d0, long n0,
    const float* s1, unsigned short* d1, long n1,
    const float* s2, unsigned short* d2, long n2,
    const float* s3, unsigned short* d3, long n3,
    const float* s4, unsigned short* d4, long n4,
    const float* s5, unsigned short* d5, long n5)
{
  const float* src; unsigned short* dst; long n;
  switch (blockIdx.y) {
    case 0: src = s0; dst = d0; n = n0; break;
    case 1: src = s1; dst = d1; n = n1; break;
    case 2: src = s2; dst = d2; n = n2; break;
    case 3: src = s3; dst = d3; n = n3; break;
    case 4: src = s4; dst = d4; n = n4; break;
    default: src = s5; dst = d5; n = n5; break;
  }
  long i = blockIdx.x * (long)blockDim.x + threadIdx.x;
  long stride = gridDim.x * (long)blockDim.x;
  for (long j = i; j * 4 < n; j += stride) {
    float4 v = *(const float4*)(src + j * 4);
    ushort4 o;
    o.x = f2b(v.x); o.y = f2b(v.y); o.z = f2b(v.z); o.w = f2b(v.w);
    *(ushort4*)(dst + j * 4) = o;
  }
}

// ---------- merged = [rms(h), rms(e_k)] in bf16 (k==0 path, h = x) ----------
__global__ __launch_bounds__(256) void rms_merge(
    const float* __restrict__ h, const float* __restrict__ x,
    const float* __restrict__ rw, unsigned short* __restrict__ merged, int koff)
{
  int r = blockIdx.x, tid = threadIdx.x;
  int b = r >> 8, p = r & 255;
  bool valid = p < PLEN;
  float4 hv = {0,0,0,0}, ev = {0,0,0,0};
  if (valid) {
    hv = *(const float4*)(h + (size_t)r * D + tid * 4);
    ev = *(const float4*)(x + ((size_t)(b * 256 + p + koff + 1)) * D + tid * 4);
  }
  float sh = hv.x*hv.x + hv.y*hv.y + hv.z*hv.z + hv.w*hv.w;
  float se = ev.x*ev.x + ev.y*ev.y + ev.z*ev.z + ev.w*ev.w;
  #pragma unroll
  for (int o = 32; o > 0; o >>= 1) { sh += __shfl_down(sh, o, 64); se += __shfl_down(se, o, 64); }
  __shared__ float ssh[4], sse[4];
  if ((tid & 63) == 0) { ssh[tid >> 6] = sh; sse[tid >> 6] = se; }
  __syncthreads();
  sh = ssh[0] + ssh[1] + ssh[2] + ssh[3];
  se = sse[0] + sse[1] + sse[2] + sse[3];
  float sc_h = rsqrtf(sh * (1.0f / D) + 1e-6f);
  float sc_e = rsqrtf(se * (1.0f / D) + 1e-6f);
  float4 wv = *(const float4*)(rw + tid * 4);
  ushort4 oh, oe;
  oh.x = f2b(hv.x * sc_h * wv.x); oh.y = f2b(hv.y * sc_h * wv.y);
  oh.z = f2b(hv.z * sc_h * wv.z); oh.w = f2b(hv.w * sc_h * wv.w);
  oe.x = f2b(ev.x * sc_e * wv.x); oe.y = f2b(ev.y * sc_e * wv.y);
  oe.z = f2b(ev.z * sc_e * wv.z); oe.w = f2b(ev.w * sc_e * wv.w);
  unsigned short* mrow = merged + (size_t)r * (2 * D);
  *(ushort4*)(mrow + tid * 4) = oh;
  *(ushort4*)(mrow + D + tid * 4) = oe;
}

// ---------- reduce 2 split-K partials: of = p0+p1 (opt), ob = bf16(p0+p1) ----------
template<bool F32OUT>
__global__ __launch_bounds__(256) void red_pv(
    const float* __restrict__ part, float* __restrict__ of, unsigned short* __restrict__ ob)
{
  int r = blockIdx.x, tid = threadIdx.x;
  float4 a = *(const float4*)(part + (size_t)r * D + tid * 4);
  float4 b = *(const float4*)(part + (size_t)MR * D + (size_t)r * D + tid * 4);
  float4 s = {a.x+b.x, a.y+b.y, a.z+b.z, a.w+b.w};
  if (F32OUT) *(float4*)(of + (size_t)r * D + tid * 4) = s;
  ushort4 o; o.x = f2b(s.x); o.y = f2b(s.y); o.z = f2b(s.z); o.w = f2b(s.w);
  *(ushort4*)(ob + (size_t)r * D + tid * 4) = o;
}

// ---------- s1 = LN(ia+ib0+ib1)*w+b -> of (f32) + ob (bf16) ----------
__global__ __launch_bounds__(256) void add_ln3(
    const float* __restrict__ ia, const float* __restrict__ ib0,
    const float* __restrict__ ib1,
    const float* __restrict__ w, const float* __restrict__ bb,
    float* __restrict__ of, unsigned short* __restrict__ ob)
{
  int r = blockIdx.x, tid = threadIdx.x;
  float4 va = *(const float4*)(ia  + (size_t)r * D + tid * 4);
  float4 v0 = *(const float4*)(ib0 + (size_t)r * D + tid * 4);
  float4 v1 = *(const float4*)(ib1 + (size_t)r * D + tid * 4);
  float4 v = {va.x+v0.x+v1.x, va.y+v0.y+v1.y, va.z+v0.z+v1.z, va.w+v0.w+v1.w};
  float s  = v.x + v.y + v.z + v.w;
  float s2 = v.x*v.x + v.y*v.y + v.z*v.z + v.w*v.w;
  #pragma unroll
  for (int o = 32; o > 0; o >>= 1) { s += __shfl_down(s, o, 64); s2 += __shfl_down(s2, o, 64); }
  __shared__ float rs[4], rq[4];
  if ((tid & 63) == 0) { rs[tid >> 6] = s; rq[tid >> 6] = s2; }
  __syncthreads();
  s  = rs[0] + rs[1] + rs[2] + rs[3];
  s2 = rq[0] + rq[1] + rq[2] + rq[3];
  float m   = s * (1.0f / D);
  float var = s2 * (1.0f / D) - m * m;
  float sc  = rsqrtf(var + 1e-5f);
  float4 wv = *(const float4*)(w + tid * 4);
  float4 bv = *(const float4*)(bb + tid * 4);
  float4 o;
  o.x = (v.x - m) * sc * wv.x + bv.x;
  o.y = (v.y - m) * sc * wv.y + bv.y;
  o.z = (v.z - m) * sc * wv.z + bv.z;
  o.w = (v.w - m) * sc * wv.w + bv.w;
  *(float4*)(of + (size_t)r * D + tid * 4) = o;
  ushort4 ub; ub.x = f2b(o.x); ub.y = f2b(o.y); ub.z = f2b(o.z); ub.w = f2b(o.w);
  *(ushort4*)(ob + (size_t)r * D + tid * 4) = ub;
}

// ---------- fused: h = LN(ia+ib0+ib1)*w+b -> ob(bf16); merged = [rms(h), rms(e)] ----------
template<bool WRITE_MERGED>
__global__ __launch_bounds__(256) void add_ln_rms3(
    const float* __restrict__ ia, const float* __restrict__ ib0,
    const float* __restrict__ ib1,
    const float* __restrict__ w, const float* __restrict__ bb,
    const float* __restrict__ rw, const float* __restrict__ x,
    unsigned short* __restrict__ ob, unsigned short* __restrict__ merged, int koff)
{
  int r = blockIdx.x, tid = threadIdx.x;
  int b = r >> 8, p = r & 255;
  bool valid = p < PLEN;
  float4 va = *(const float4*)(ia  + (size_t)r * D + tid * 4);
  float4 v0 = *(const float4*)(ib0 + (size_t)r * D + tid * 4);
  float4 v1 = *(const float4*)(ib1 + (size_t)r * D + tid * 4);
  float4 v = {va.x+v0.x+v1.x, va.y+v0.y+v1.y, va.z+v0.z+v1.z, va.w+v0.w+v1.w};
  float4 ev = {0,0,0,0};
  if (WRITE_MERGED && valid)
    ev = *(const float4*)(x + ((size_t)(b * 256 + p + koff + 1)) * D + tid * 4);
  float s  = v.x + v.y + v.z + v.w;
  float s2 = v.x*v.x + v.y*v.y + v.z*v.z + v.w*v.w;
  float se = ev.x*ev.x + ev.y*ev.y + ev.z*ev.z + ev.w*ev.w;
  #pragma unroll
  for (int o = 32; o > 0; o >>= 1) {
    s += __shfl_down(s, o, 64); s2 += __shfl_down(s2, o, 64); se += __shfl_down(se, o, 64);
  }
  __shared__ float rs[4], rq[4], re[4], rh[4];
  if ((tid & 63) == 0) { rs[tid >> 6] = s; rq[tid >> 6] = s2; re[tid >> 6] = se; }
  __syncthreads();
  s  = rs[0] + rs[1] + rs[2] + rs[3];
  s2 = rq[0] + rq[1] + rq[2] + rq[3];
  se = re[0] + re[1] + re[2] + re[3];
  float m   = s * (1.0f / D);
  float var = s2 * (1.0f / D) - m * m;
  float sc  = rsqrtf(var + 1e-5f);
  float4 wv = *(const float4*)(w + tid * 4);
  float4 bv = *(const float4*)(bb + tid * 4);
  float4 o;
  o.x = (v.x - m) * sc * wv.x + bv.x;
  o.y = (v.y - m) * sc * wv.y + bv.y;
  o.z = (v.z - m) * sc * wv.z + bv.z;
  o.w = (v.w - m) * sc * wv.w + bv.w;
  ushort4 ub; ub.x = f2b(o.x); ub.y = f2b(o.y); ub.z = f2b(o.z); ub.w = f2b(o.w);
  *(ushort4*)(ob + (size_t)r * D + tid * 4) = ub;
  if (WRITE_MERGED) {
    float sh = o.x*o.x + o.y*o.y + o.z*o.z + o.w*o.w;
    #pragma unroll
    for (int q2 = 32; q2 > 0; q2 >>= 1) sh += __shfl_down(sh, q2, 64);
    if ((tid & 63) == 0) rh[tid >> 6] = sh;
    __syncthreads();
    sh = rh[0] + rh[1] + rh[2] + rh[3];
    float sc_h = rsqrtf(sh * (1.0f / D) + 1e-6f);
    float sc_e = rsqrtf(se * (1.0f / D) + 1e-6f);
    float4 rwv = *(const float4*)(rw + tid * 4);
    ushort4 oh, oe;
    oh.x = f2b(o.x * sc_h * rwv.x); oh.y = f2b(o.y * sc_h * rwv.y);
    oh.z = f2b(o.z * sc_h * rwv.z); oh.w = f2b(o.w * sc_h * rwv.w);
    oe.x = f2b(ev.x * sc_e * rwv.x); oe.y = f2b(ev.y * sc_e * rwv.y);
    oe.z = f2b(ev.z * sc_e * rwv.z); oe.w = f2b(ev.w * sc_e * rwv.w);
    unsigned short* mrow = merged + (size_t)r * (2 * D);
    *(ushort4*)(mrow + tid * 4) = oh;
    *(ushort4*)(mrow + D + tid * 4) = oe;
  }
}

// ---------- trunk GEMM: 64x64 tile, 4 waves, BK=64, 3-deep counted vmcnt, optional split-K ----------
// Side-band cvt: blocks with bx >= nx (and by==0, z==0) convert cvt_cnt float4-groups of the
// embed matrix (grid-stride); other bx>=nx blocks exit. Uses idle wave slots + BW headroom.
template<bool BIAS, bool RELU, bool OF32, bool OB16, int KS>
__global__ __launch_bounds__(256) void gemm2(
    const unsigned short* __restrict__ A, const unsigned short* __restrict__ Bt,
    const float* __restrict__ bias, float* __restrict__ Cf,
    unsigned short* __restrict__ Cb, int N, int K, int nx,
    const float* __restrict__ cvt_src, unsigned short* __restrict__ cvt_dst, long cvt_cnt)
{
  const int z = (KS > 1) ? blockIdx.z : 0;
  if ((int)blockIdx.x >= nx) {
    if (z == 0 && blockIdx.y == 0 && cvt_cnt > 0) {
      long lanes = (long)(gridDim.x - nx) * 256;
      for (long j = (long)((int)blockIdx.x - nx) * 256 + threadIdx.x; j < cvt_cnt; j += lanes) {
        float4 v = *(const float4*)(cvt_src + j * 4);
        ushort4 o; o.x = f2b(v.x); o.y = f2b(v.y); o.z = f2b(v.z); o.w = f2b(v.w);
        *(ushort4*)(cvt_dst + j * 4) = o;
      }
    }
    return;
  }
  constexpr int BK = 64;
  __shared__ __align__(16) unsigned short As[3][64 * BK];
  __shared__ __align__(16) unsigned short Bs[3][64 * BK];
  const int tid = threadIdx.x;
  const int lane = tid & 63, wave = tid >> 6;
  const int wm = wave >> 1, wn = wave & 1;
  const int l16 = lane & 15, lk = lane >> 4;
  const int tm = blockIdx.y * 64, tn = blockIdx.x * 64;
  const int Keff = K / KS;
  const int kbase = z * Keff;
  const int NT = Keff / BK;
  const size_t zoff = (size_t)z * gridDim.y * 64 * N;

  auto stage = [&](int t, int s) {
    #pragma unroll
    for (int i = 0; i < 2; ++i) {
      int c = i * 256 + tid;
      int rr = c >> 3, qq = c & 7;
      int k8 = qq ^ (rr & 7);
      gload16(A + (size_t)(tm + rr) * K + kbase + t * BK + k8 * 8, &As[s][c * 8]);
    }
    #pragma unroll
    for (int i = 0; i < 2; ++i) {
      int c = i * 256 + tid;
      int rr = c >> 3, qq = c & 7;
      int k8 = qq ^ (rr & 7);
      gload16(Bt + (size_t)(tn + rr) * K + kbase + t * BK + k8 * 8, &Bs[s][c * 8]);
    }
  };

  f32x4 acc[2][2] = {};
  stage(0, 0);
  stage(1, 1);
  for (int t = 0; t < NT; ++t) {
    int t2 = (t + 2 < NT) ? t + 2 : NT - 1;
    stage(t2, (t + 2) % 3);
    asm volatile("s_waitcnt vmcnt(8)" ::: "memory");
    __builtin_amdgcn_s_barrier();
    const unsigned short* as = &As[t % 3][0];
    const unsigned short* bs = &Bs[t % 3][0];
    #pragma unroll
    for (int kk = 0; kk < 2; ++kk) {
      bf16x8 af[2], bg[2];
      #pragma unroll
      for (int mi = 0; mi < 2; ++mi) {
        int row = wm * 32 + mi * 16 + l16;
        int ch = (kk * 4 + lk) ^ (row & 7);
        af[mi] = *(const bf16x8*)(as + row * 64 + ch * 8);
      }
      #pragma unroll
      for (int ni = 0; ni < 2; ++ni) {
        int row = wn * 32 + ni * 16 + l16;
        int ch = (kk * 4 + lk) ^ (row & 7);
        bg[ni] = *(const bf16x8*)(bs + row * 64 + ch * 8);
      }
      #pragma unroll
      for (int mi = 0; mi < 2; ++mi)
        #pragma unroll
        for (int ni = 0; ni < 2; ++ni)
          acc[mi][ni] = __builtin_amdgcn_mfma_f32_16x16x32_bf16(af[mi], bg[ni], acc[mi][ni], 0, 0, 0);
    }
    __builtin_amdgcn_s_barrier();
  }
  asm volatile("s_waitcnt vmcnt(0)" ::: "memory");

  const int rbase = tm + wm * 32, cbase = tn + wn * 32;
  #pragma unroll
  for (int ni = 0; ni < 2; ++ni) {
    int col = cbase + ni * 16 + l16;
    float bvv = (BIAS && z == 0) ? bias[col] : 0.0f;
    #pragma unroll
    for (int mi = 0; mi < 2; ++mi) {
      #pragma unroll
      for (int rr = 0; rr < 4; ++rr) {
        int row = rbase + mi * 16 + lk * 4 + rr;
        float v = acc[mi][ni][rr] + bvv;
        if (RELU) v = fmaxf(v, 0.0f);
        size_t idx = (size_t)row * N + col;
        if (OF32) Cf[zoff + idx] = v;
        if (OB16) Cb[idx] = f2b(v);
      }
    }
  }
}

// ---------- logits: BM=256 x BN=256, BK=32, 8 waves (2Mx4N), 3-parity ring, lead 2 ----------
// R13 verbatim (best verified: 210us, 0 bank conflicts): 8-quad swizzle write k8=qq^((rr>>1)&3),
// read ch=lk^((row>>1)&3).
__global__ __launch_bounds__(512, 2) void gemm_logits256(
    const unsigned short* __restrict__ A, const unsigned short* __restrict__ E,
    float* __restrict__ Out)
{
  constexpr int NT  = 32;            // K=1024 / BK=32
  constexpr int NWG = 6 * 197;       // M-tiles x N-panels(256)
  __shared__ __align__(16) unsigned short Asl[3][256 * 32];   // 3 x 16KB
  __shared__ __align__(16) unsigned short Bsl[3][256 * 32];   // 3 x 16KB

  const int tid  = threadIdx.x;
  const int lane = tid & 63, wave = tid >> 6;
  const int wm = wave >> 2, wn = wave & 3;       // 2M x 4N, per-wave 128x64
  const int l16 = lane & 15, lk = lane >> 4;

  // bijective XCD swizzle (m204): 1182 = 8*147 + 6
  int orig = blockIdx.x;
  int xcd = orig & 7, local = orig >> 3;
  constexpr int q = NWG / 8, r8 = NWG % 8;
  int wgid = (xcd < r8 ? xcd * (q + 1) : r8 * (q + 1) + (xcd - r8) * q) + local;
  const int tm = (wgid % 6) * 256;   // 6 consecutive wgid share the same B panel
  const int tn = (wgid / 6) * 256;

  f32x4 acc[8][4] = {};

  auto stageA = [&](int t, int s) {
    #pragma unroll
    for (int i = 0; i < 2; ++i) {                 // 1024 chunks = 16KB
      int c = i * 512 + tid;
      int rr = c >> 2, qq = c & 3;
      int k8 = qq ^ ((rr >> 1) & 3);              // 8-quad involution
      gload16(A + (size_t)(tm + rr) * 1024 + t * 32 + k8 * 8, &Asl[s][c * 8]);
    }
  };
  auto stageB = [&](int t, int s) {
    #pragma unroll
    for (int i = 0; i < 2; ++i) {                 // 1024 chunks = 16KB
      int c = i * 512 + tid;
      int rr = c >> 2, qq = c & 3;
      int k8 = qq ^ ((rr >> 1) & 3);
      int row = tn + rr; if (row > V - 1) row = V - 1;   // clamp OOB vocab rows
      gload16(E + (size_t)row * 1024 + t * 32 + k8 * 8, &Bsl[s][c * 8]);
    }
  };

  // prologue: steps 0,1 fully in flight (8 instr/wave)
  stageA(0, 0); stageB(0, 0);
  stageA(1, 1); stageB(1, 1);

  for (int t = 0; t < NT; ++t) {
    const int s  = t % 3;
    const int t2 = (t + 2 < NT) ? t + 2 : NT - 1;   // dummy tail keeps vmcnt uniform
    const int s2 = (t + 2) % 3;                     // distinct from s and (t+1)%3
    asm volatile("s_waitcnt vmcnt(4)" ::: "memory"); // step-t landed (t+1's 4 in flight)
    __builtin_amdgcn_s_barrier();                    // step-t chunks visible to all waves
    const unsigned short* as = &Asl[s][0];
    const unsigned short* bs = &Bsl[s][0];
    bf16x8 af[8], bg[4];
    #pragma unroll
    for (int mi = 0; mi < 8; ++mi) {
      int row = wm * 128 + mi * 16 + l16;
      int ch = lk ^ ((row >> 1) & 3);
      af[mi] = *(const bf16x8*)(as + row * 32 + ch * 8);
    }
    #pragma unroll
    for (int ni = 0; ni < 4; ++ni) {
      int row = wn * 64 + ni * 16 + l16;
      int ch = lk ^ ((row >> 1) & 3);
      bg[ni] = *(const bf16x8*)(bs + row * 32 + ch * 8);
    }
    stageA(t2, s2); stageB(t2, s2);                  // 4 instr; lead = 2 steps
    __builtin_amdgcn_s_setprio(1);
    #pragma unroll
    for (int mi = 0; mi < 8; ++mi)
      #pragma unroll
      for (int ni = 0; ni < 4; ++ni)
        acc[mi][ni] = __builtin_amdgcn_mfma_f32_16x16x32_bf16(af[mi], bg[ni], acc[mi][ni], 0, 0, 0);
    __builtin_amdgcn_s_setprio(0);
  }
  asm volatile("s_waitcnt vmcnt(0)" ::: "memory");   // drain dummies before stores/endpgm

  #pragma unroll
  for (int mi = 0; mi < 8; ++mi) {
    #pragma unroll
    for (int rr = 0; rr < 4; ++rr) {
      int row = tm + wm * 128 + mi * 16 + lk * 4 + rr;  // 0..1535 padded
      int kk = row >> 9, bp = row & 511, b = bp >> 8, p = bp & 255;
      if (p >= PLEN) continue;
      size_t obase = ((size_t)((b * PLEN + p) * KD + kk)) * V;
      #pragma unroll
      for (int ni = 0; ni < 4; ++ni) {
        int col = tn + wn * 64 + ni * 16 + l16;
        if (col < V) Out[obase + col] = acc[mi][ni][rr];
      }
    }
  }
}

extern "C" void kernel_launch(void* const* d_in, const int* in_sizes, int n_in,
                              void* d_out, int out_size, void* d_ws, size_t ws_size,
                              hipStream_t stream)
{
  (void)in_sizes; (void)n_in; (void)out_size; (void)ws_size;
  const float* x      = (const float*)d_in[0];
  const float* embedw = (const float*)d_in[1];
  const float* rmsw   = (const float*)d_in[2];
  const float* projw  = (const float*)d_in[3];
  const float* projb  = (const float*)d_in[4];
  const float* ainw   = (const float*)d_in[5];
  const float* ainb   = (const float*)d_in[6];
  const float* aoutw  = (const float*)d_in[7];
  const float* aoutb  = (const float*)d_in[8];
  const float* ff1w   = (const float*)d_in[9];
  const float* ff1b   = (const float*)d_in[10];
  const float* ff2w   = (const float*)d_in[11];
  const float* ff2b   = (const float*)d_in[12];
  const float* ln1w   = (const float*)d_in[13];
  const float* ln1b   = (const float*)d_in[14];
  const float* ln2w   = (const float*)d_in[15];
  const float* ln2b   = (const float*)d_in[16];
  float* out = (float*)d_out;

  char* ws = (char*)d_ws;
  size_t off = 0;
  auto alloc = [&](size_t bytes) -> void* {
    void* ptr = ws + off;
    off = (off + bytes + 255) & ~(size_t)255;
    return ptr;
  };
  unsigned short* embed_b = (unsigned short*)alloc((size_t)V * D * 2);
  unsigned short* projw_b = (unsigned short*)alloc((size_t)KD * D * 2 * D * 2);
  unsigned short* ainw_b  = (unsigned short*)alloc((size_t)KD * D * D * 2);   // V-slice only
  unsigned short* aoutw_b = (unsigned short*)alloc((size_t)KD * D * D * 2);
  unsigned short* ff1w_b  = (unsigned short*)alloc((size_t)KD * DFF * D * 2);
  unsigned short* ff2w_b  = (unsigned short*)alloc((size_t)KD * D * DFF * 2);
  unsigned short* h_all   = (unsigned short*)alloc((size_t)KD * MR * D * 2);
  unsigned short* merged  = (unsigned short*)alloc((size_t)MR * 2 * D * 2);
  float*          pp      = (float*)alloc((size_t)2 * MR * D * 4);   // proj/v split-K partials
  float*          p_f     = (float*)alloc((size_t)MR * D * 4);
  unsigned short* p_b     = (unsigned short*)alloc((size_t)MR * D * 2);
  unsigned short* v_b     = (unsigned short*)alloc((size_t)MR * D * 2);
  float*          sa_f    = (float*)alloc((size_t)2 * MR * D * 4);   // split-K partials
  float*          s1_f    = (float*)alloc((size_t)MR * D * 4);
  unsigned short* s1_b    = (unsigned short*)alloc((size_t)MR * D * 2);
  unsigned short* ff_b    = (unsigned short*)alloc((size_t)MR * DFF * 2);
  float*          ff2_f   = (float*)alloc((size_t)2 * MR * D * 4);   // split-K partials

  // weight converts (embed is folded into the 15 trunk GEMM dispatches below)
  cvt_all<<<dim3(512, 2), dim3(256), 0, stream>>>(
      projw,  projw_b, (long)KD * D * 2 * D,
      ff1w,   ff1w_b,  (long)KD * DFF * D,
      (const float*)nullptr, (unsigned short*)nullptr, 0,
      (const float*)nullptr, (unsigned short*)nullptr, 0,
      (const float*)nullptr, (unsigned short*)nullptr, 0,
      (const float*)nullptr, (unsigned short*)nullptr, 0);
  cvt_all<<<dim3(512, 6), dim3(256), 0, stream>>>(
      ainw + (size_t)0 * 3 * D * D + 2 * D * D, ainw_b + (size_t)0 * D * D, (long)D * D,
      ainw + (size_t)1 * 3 * D * D + 2 * D * D, ainw_b + (size_t)1 * D * D, (long)D * D,
      ainw + (size_t)2 * 3 * D * D + 2 * D * D, ainw_b + (size_t)2 * D * D, (long)D * D,
      aoutw,  aoutw_b, (long)KD * D * D,
      ff2w,   ff2w_b,  (long)KD * D * DFF,
      (const float*)nullptr, (unsigned short*)nullptr, 0);

  rms_merge<<<dim3(MR), dim3(256), 0, stream>>>(x, x, rmsw, merged, 0);

  // embed cvt slices: 15 trunk GEMM dispatches, each converts 1/15 of V*D/4 float4-groups
  const long N4 = (long)V * D / 4;
  const long CH = (N4 + 14) / 15;
  auto slc = [&](int si, const float*& s, unsigned short*& d, long& n) {
    long o = (long)si * CH;
    n = (o < N4) ? ((N4 - o < CH) ? (N4 - o) : CH) : 0;
    s = embedw + o * 4; d = embed_b + o * 4;
  };

  for (int k = 0; k < KD; ++k) {
    const float* cs; unsigned short* cd; long cn;
    // p = merged @ proj_w[k]^T + proj_b[k]   (K=2048) -- split-K=2 -> pp; reduce -> p_f,p_b
    slc(k * 5 + 0, cs, cd, cn);
    gemm2<true,false,true,false,2><<<dim3(D/64 + CVTB, MR/64, 2), dim3(256), 0, stream>>>(
        merged, projw_b + (size_t)k * D * 2 * D, projb + (size_t)k * D, pp, (unsigned short*)nullptr,
        D, 2 * D, D/64, cs, cd, cn);
    red_pv<true><<<dim3(MR), dim3(256), 0, stream>>>(pp, p_f, p_b);
    // v = p @ wv^T + bv   (K=1024) -- split-K=2 -> pp; reduce -> v_b
    slc(k * 5 + 1, cs, cd, cn);
    gemm2<true,false,true,false,2><<<dim3(D/64 + CVTB, MR/64, 2), dim3(256), 0, stream>>>(
        p_b, ainw_b + (size_t)k * D * D, ainb + (size_t)k * 3 * D + 2 * D, pp, (unsigned short*)nullptr,
        D, D, D/64, cs, cd, cn);
    red_pv<false><<<dim3(MR), dim3(256), 0, stream>>>(pp, (float*)nullptr, v_b);
    // sa = v @ attn_out_w[k]^T + b -- split-K=2, partials summed by add_ln3
    slc(k * 5 + 2, cs, cd, cn);
    gemm2<true,false,true,false,2><<<dim3(D/64 + CVTB, MR/64, 2), dim3(256), 0, stream>>>(
        v_b, aoutw_b + (size_t)k * D * D, aoutb + (size_t)k * D, sa_f, (unsigned short*)nullptr,
        D, D, D/64, cs, cd, cn);
    // s1 = LN(p + sa0 + sa1)
    add_ln3<<<dim3(MR), dim3(256), 0, stream>>>(
        p_f, sa_f, sa_f + (size_t)MR * D, ln1w + (size_t)k * D, ln1b + (size_t)k * D, s1_f, s1_b);
    // ff = relu(s1 @ ff1_w[k]^T + b)   (N=2048)
    slc(k * 5 + 3, cs, cd, cn);
    gemm2<true,true,false,true,1><<<dim3(DFF/64 + CVTB, MR/64), dim3(256), 0, stream>>>(
        s1_b, ff1w_b + (size_t)k * DFF * D, ff1b + (size_t)k * DFF, (float*)nullptr, ff_b,
        DFF, D, DFF/64, cs, cd, cn);
    // ff2 = ff @ ff2_w[k]^T + b   (K=2048) -- split-K=2, partials summed by add_ln_rms3
    slc(k * 5 + 4, cs, cd, cn);
    gemm2<true,false,true,false,2><<<dim3(D/64 + CVTB, MR/64, 2), dim3(256), 0, stream>>>(
        ff_b, ff2w_b + (size_t)k * D * DFF, ff2b + (size_t)k * D, ff2_f, (unsigned short*)nullptr,
        D, 2 * D, D/64, cs, cd, cn);
    // h = LN(s1 + ff2a + ff2b) -> h_all[k]; for k<2 also merged for depth k+1
    if (k < KD - 1)
      add_ln_rms3<true><<<dim3(MR), dim3(256), 0, stream>>>(
          s1_f, ff2_f, ff2_f + (size_t)MR * D, ln2w + (size_t)k * D, ln2b + (size_t)k * D, rmsw, x,
          h_all + (size_t)k * MR * D, merged, k + 1);
    else
      add_ln_rms3<false><<<dim3(MR), dim3(256), 0, stream>>>(
          s1_f, ff2_f, ff2_f + (size_t)MR * D, ln2w + (size_t)k * D, ln2b + (size_t)k * D, rmsw, x,
          h_all + (size_t)k * MR * D, (unsigned short*)nullptr, 0);
  }

  // logits: (1536 x 1024) @ (50257 x 1024)^T, 256^2 3-parity deep pipeline
  gemm_logits256<<<dim3(6 * 197), dim3(512), 0, stream>>>(h_all, embed_b, out);
}

// Round 16
// 492.950 us; speedup vs baseline: 1.1894x; 1.1894x over previous
//
#include <hip/hip_runtime.h>
#include <stdint.h>

#define DEV __device__ __forceinline__

using bf16x8 = __attribute__((ext_vector_type(8))) __bf16;
using f32x4  = __attribute__((ext_vector_type(4))) float;

static constexpr int D    = 1024;
static constexpr int V    = 50257;
static constexpr int DFF  = 2048;
static constexpr int KD   = 3;     // depth
static constexpr int MR   = 512;   // padded rows per depth: r = b*256 + p
static constexpr int PLEN = 253;

DEV unsigned short f2b(float f) {
  unsigned int u = __float_as_uint(f);
  u += 0x7fffu + ((u >> 16) & 1u);   // RNE
  return (unsigned short)(u >> 16);
}

DEV void gload16(const void* g, void* l) {
  __builtin_amdgcn_global_load_lds(
      (const __attribute__((address_space(1))) unsigned int*)g,
      (__attribute__((address_space(3))) unsigned int*)l, 16, 0, 0);
}

// ---------- 6-slice f32 -> bf16 convert (grid-y picks slice); nt loads (read-once data) ----------
__global__ void cvt_all(
    const float* s0, unsigned short* d0, long n0,
    const float* s1, unsigned short* d1, long n1,
    const float* s2, unsigned short* d2, long n2,
    const float* s3, unsigned short* d3, long n3,
    const float* s4, unsigned short* d4, long n4,
    const float* s5, unsigned short* d5, long n5)
{
  const float* src; unsigned short* dst; long n;
  switch (blockIdx.y) {
    case 0: src = s0; dst = d0; n = n0; break;
    case 1: src = s1; dst = d1; n = n1; break;
    case 2: src = s2; dst = d2; n = n2; break;
    case 3: src = s3; dst = d3; n = n3; break;
    case 4: src = s4; dst = d4; n = n4; break;
    default: src = s5; dst = d5; n = n5; break;
  }
  long i = blockIdx.x * (long)blockDim.x + threadIdx.x;
  long stride = gridDim.x * (long)blockDim.x;
  for (long j = i; j * 4 < n; j += stride) {
    const f32x4* sp = (const f32x4*)(src + j * 4);     // ext_vector type: valid for nt builtin
    f32x4 v = __builtin_nontemporal_load(sp);          // read-once: don't pollute L2/L3
    ushort4 o;
    o.x = f2b(v.x); o.y = f2b(v.y); o.z = f2b(v.z); o.w = f2b(v.w);
    *(ushort4*)(dst + j * 4) = o;
  }
}

// ---------- merged = [rms(h), rms(e_k)] in bf16 (k==0 path, h = x) ----------
__global__ __launch_bounds__(256) void rms_merge(
    const float* __restrict__ h, const float* __restrict__ x,
    const float* __restrict__ rw, unsigned short* __restrict__ merged, int koff)
{
  int r = blockIdx.x, tid = threadIdx.x;
  int b = r >> 8, p = r & 255;
  bool valid = p < PLEN;
  float4 hv = {0,0,0,0}, ev = {0,0,0,0};
  if (valid) {
    hv = *(const float4*)(h + (size_t)r * D + tid * 4);
    ev = *(const float4*)(x + ((size_t)(b * 256 + p + koff + 1)) * D + tid * 4);
  }
  float sh = hv.x*hv.x + hv.y*hv.y + hv.z*hv.z + hv.w*hv.w;
  float se = ev.x*ev.x + ev.y*ev.y + ev.z*ev.z + ev.w*ev.w;
  #pragma unroll
  for (int o = 32; o > 0; o >>= 1) { sh += __shfl_down(sh, o, 64); se += __shfl_down(se, o, 64); }
  __shared__ float ssh[4], sse[4];
  if ((tid & 63) == 0) { ssh[tid >> 6] = sh; sse[tid >> 6] = se; }
  __syncthreads();
  sh = ssh[0] + ssh[1] + ssh[2] + ssh[3];
  se = sse[0] + sse[1] + sse[2] + sse[3];
  float sc_h = rsqrtf(sh * (1.0f / D) + 1e-6f);
  float sc_e = rsqrtf(se * (1.0f / D) + 1e-6f);
  float4 wv = *(const float4*)(rw + tid * 4);
  ushort4 oh, oe;
  oh.x = f2b(hv.x * sc_h * wv.x); oh.y = f2b(hv.y * sc_h * wv.y);
  oh.z = f2b(hv.z * sc_h * wv.z); oh.w = f2b(hv.w * sc_h * wv.w);
  oe.x = f2b(ev.x * sc_e * wv.x); oe.y = f2b(ev.y * sc_e * wv.y);
  oe.z = f2b(ev.z * sc_e * wv.z); oe.w = f2b(ev.w * sc_e * wv.w);
  unsigned short* mrow = merged + (size_t)r * (2 * D);
  *(ushort4*)(mrow + tid * 4) = oh;
  *(ushort4*)(mrow + D + tid * 4) = oe;
}

// ---------- reduce 2 split-K partials: of = p0+p1 (opt), ob = bf16(p0+p1) ----------
template<bool F32OUT>
__global__ __launch_bounds__(256) void red_pv(
    const float* __restrict__ part, float* __restrict__ of, unsigned short* __restrict__ ob)
{
  int r = blockIdx.x, tid = threadIdx.x;
  float4 a = *(const float4*)(part + (size_t)r * D + tid * 4);
  float4 b = *(const float4*)(part + (size_t)MR * D + (size_t)r * D + tid * 4);
  float4 s = {a.x+b.x, a.y+b.y, a.z+b.z, a.w+b.w};
  if (F32OUT) *(float4*)(of + (size_t)r * D + tid * 4) = s;
  ushort4 o; o.x = f2b(s.x); o.y = f2b(s.y); o.z = f2b(s.z); o.w = f2b(s.w);
  *(ushort4*)(ob + (size_t)r * D + tid * 4) = o;
}

// ---------- s1 = LN(ia+ib0+ib1)*w+b -> of (f32) + ob (bf16) ----------
__global__ __launch_bounds__(256) void add_ln3(
    const float* __restrict__ ia, const float* __restrict__ ib0,
    const float* __restrict__ ib1,
    const float* __restrict__ w, const float* __restrict__ bb,
    float* __restrict__ of, unsigned short* __restrict__ ob)
{
  int r = blockIdx.x, tid = threadIdx.x;
  float4 va = *(const float4*)(ia  + (size_t)r * D + tid * 4);
  float4 v0 = *(const float4*)(ib0 + (size_t)r * D + tid * 4);
  float4 v1 = *(const float4*)(ib1 + (size_t)r * D + tid * 4);
  float4 v = {va.x+v0.x+v1.x, va.y+v0.y+v1.y, va.z+v0.z+v1.z, va.w+v0.w+v1.w};
  float s  = v.x + v.y + v.z + v.w;
  float s2 = v.x*v.x + v.y*v.y + v.z*v.z + v.w*v.w;
  #pragma unroll
  for (int o = 32; o > 0; o >>= 1) { s += __shfl_down(s, o, 64); s2 += __shfl_down(s2, o, 64); }
  __shared__ float rs[4], rq[4];
  if ((tid & 63) == 0) { rs[tid >> 6] = s; rq[tid >> 6] = s2; }
  __syncthreads();
  s  = rs[0] + rs[1] + rs[2] + rs[3];
  s2 = rq[0] + rq[1] + rq[2] + rq[3];
  float m   = s * (1.0f / D);
  float var = s2 * (1.0f / D) - m * m;
  float sc  = rsqrtf(var + 1e-5f);
  float4 wv = *(const float4*)(w + tid * 4);
  float4 bv = *(const float4*)(bb + tid * 4);
  float4 o;
  o.x = (v.x - m) * sc * wv.x + bv.x;
  o.y = (v.y - m) * sc * wv.y + bv.y;
  o.z = (v.z - m) * sc * wv.z + bv.z;
  o.w = (v.w - m) * sc * wv.w + bv.w;
  *(float4*)(of + (size_t)r * D + tid * 4) = o;
  ushort4 ub; ub.x = f2b(o.x); ub.y = f2b(o.y); ub.z = f2b(o.z); ub.w = f2b(o.w);
  *(ushort4*)(ob + (size_t)r * D + tid * 4) = ub;
}

// ---------- fused: h = LN(ia+ib0+ib1)*w+b -> ob(bf16); merged = [rms(h), rms(e)] ----------
template<bool WRITE_MERGED>
__global__ __launch_bounds__(256) void add_ln_rms3(
    const float* __restrict__ ia, const float* __restrict__ ib0,
    const float* __restrict__ ib1,
    const float* __restrict__ w, const float* __restrict__ bb,
    const float* __restrict__ rw, const float* __restrict__ x,
    unsigned short* __restrict__ ob, unsigned short* __restrict__ merged, int koff)
{
  int r = blockIdx.x, tid = threadIdx.x;
  int b = r >> 8, p = r & 255;
  bool valid = p < PLEN;
  float4 va = *(const float4*)(ia  + (size_t)r * D + tid * 4);
  float4 v0 = *(const float4*)(ib0 + (size_t)r * D + tid * 4);
  float4 v1 = *(const float4*)(ib1 + (size_t)r * D + tid * 4);
  float4 v = {va.x+v0.x+v1.x, va.y+v0.y+v1.y, va.z+v0.z+v1.z, va.w+v0.w+v1.w};
  float4 ev = {0,0,0,0};
  if (WRITE_MERGED && valid)
    ev = *(const float4*)(x + ((size_t)(b * 256 + p + koff + 1)) * D + tid * 4);
  float s  = v.x + v.y + v.z + v.w;
  float s2 = v.x*v.x + v.y*v.y + v.z*v.z + v.w*v.w;
  float se = ev.x*ev.x + ev.y*ev.y + ev.z*ev.z + ev.w*ev.w;
  #pragma unroll
  for (int o = 32; o > 0; o >>= 1) {
    s += __shfl_down(s, o, 64); s2 += __shfl_down(s2, o, 64); se += __shfl_down(se, o, 64);
  }
  __shared__ float rs[4], rq[4], re[4], rh[4];
  if ((tid & 63) == 0) { rs[tid >> 6] = s; rq[tid >> 6] = s2; re[tid >> 6] = se; }
  __syncthreads();
  s  = rs[0] + rs[1] + rs[2] + rs[3];
  s2 = rq[0] + rq[1] + rq[2] + rq[3];
  se = re[0] + re[1] + re[2] + re[3];
  float m   = s * (1.0f / D);
  float var = s2 * (1.0f / D) - m * m;
  float sc  = rsqrtf(var + 1e-5f);
  float4 wv = *(const float4*)(w + tid * 4);
  float4 bv = *(const float4*)(bb + tid * 4);
  float4 o;
  o.x = (v.x - m) * sc * wv.x + bv.x;
  o.y = (v.y - m) * sc * wv.y + bv.y;
  o.z = (v.z - m) * sc * wv.z + bv.z;
  o.w = (v.w - m) * sc * wv.w + bv.w;
  ushort4 ub; ub.x = f2b(o.x); ub.y = f2b(o.y); ub.z = f2b(o.z); ub.w = f2b(o.w);
  *(ushort4*)(ob + (size_t)r * D + tid * 4) = ub;
  if (WRITE_MERGED) {
    float sh = o.x*o.x + o.y*o.y + o.z*o.z + o.w*o.w;
    #pragma unroll
    for (int q2 = 32; q2 > 0; q2 >>= 1) sh += __shfl_down(sh, q2, 64);
    if ((tid & 63) == 0) rh[tid >> 6] = sh;
    __syncthreads();
    sh = rh[0] + rh[1] + rh[2] + rh[3];
    float sc_h = rsqrtf(sh * (1.0f / D) + 1e-6f);
    float sc_e = rsqrtf(se * (1.0f / D) + 1e-6f);
    float4 rwv = *(const float4*)(rw + tid * 4);
    ushort4 oh, oe;
    oh.x = f2b(o.x * sc_h * rwv.x); oh.y = f2b(o.y * sc_h * rwv.y);
    oh.z = f2b(o.z * sc_h * rwv.z); oh.w = f2b(o.w * sc_h * rwv.w);
    oe.x = f2b(ev.x * sc_e * rwv.x); oe.y = f2b(ev.y * sc_e * rwv.y);
    oe.z = f2b(ev.z * sc_e * rwv.z); oe.w = f2b(ev.w * sc_e * rwv.w);
    unsigned short* mrow = merged + (size_t)r * (2 * D);
    *(ushort4*)(mrow + tid * 4) = oh;
    *(ushort4*)(mrow + D + tid * 4) = oe;
  }
}

// ---------- trunk GEMM: 64x64 tile, 4 waves, BK=64, 3-deep counted vmcnt, optional split-K ----------
template<bool BIAS, bool RELU, bool OF32, bool OB16, int KS>
__global__ __launch_bounds__(256) void gemm2(
    const unsigned short* __restrict__ A, const unsigned short* __restrict__ Bt,
    const float* __restrict__ bias, float* __restrict__ Cf,
    unsigned short* __restrict__ Cb, int N, int K)
{
  constexpr int BK = 64;
  __shared__ __align__(16) unsigned short As[3][64 * BK];
  __shared__ __align__(16) unsigned short Bs[3][64 * BK];
  const int tid = threadIdx.x;
  const int lane = tid & 63, wave = tid >> 6;
  const int wm = wave >> 1, wn = wave & 1;
  const int l16 = lane & 15, lk = lane >> 4;
  const int tm = blockIdx.y * 64, tn = blockIdx.x * 64;
  const int z = (KS > 1) ? blockIdx.z : 0;
  const int Keff = K / KS;
  const int kbase = z * Keff;
  const int NT = Keff / BK;
  const size_t zoff = (size_t)z * gridDim.y * 64 * N;

  auto stage = [&](int t, int s) {
    #pragma unroll
    for (int i = 0; i < 2; ++i) {
      int c = i * 256 + tid;
      int rr = c >> 3, qq = c & 7;
      int k8 = qq ^ (rr & 7);
      gload16(A + (size_t)(tm + rr) * K + kbase + t * BK + k8 * 8, &As[s][c * 8]);
    }
    #pragma unroll
    for (int i = 0; i < 2; ++i) {
      int c = i * 256 + tid;
      int rr = c >> 3, qq = c & 7;
      int k8 = qq ^ (rr & 7);
      gload16(Bt + (size_t)(tn + rr) * K + kbase + t * BK + k8 * 8, &Bs[s][c * 8]);
    }
  };

  f32x4 acc[2][2] = {};
  stage(0, 0);
  stage(1, 1);
  for (int t = 0; t < NT; ++t) {
    int t2 = (t + 2 < NT) ? t + 2 : NT - 1;
    stage(t2, (t + 2) % 3);
    asm volatile("s_waitcnt vmcnt(8)" ::: "memory");
    __builtin_amdgcn_s_barrier();
    const unsigned short* as = &As[t % 3][0];
    const unsigned short* bs = &Bs[t % 3][0];
    #pragma unroll
    for (int kk = 0; kk < 2; ++kk) {
      bf16x8 af[2], bg[2];
      #pragma unroll
      for (int mi = 0; mi < 2; ++mi) {
        int row = wm * 32 + mi * 16 + l16;
        int ch = (kk * 4 + lk) ^ (row & 7);
        af[mi] = *(const bf16x8*)(as + row * 64 + ch * 8);
      }
      #pragma unroll
      for (int ni = 0; ni < 2; ++ni) {
        int row = wn * 32 + ni * 16 + l16;
        int ch = (kk * 4 + lk) ^ (row & 7);
        bg[ni] = *(const bf16x8*)(bs + row * 64 + ch * 8);
      }
      #pragma unroll
      for (int mi = 0; mi < 2; ++mi)
        #pragma unroll
        for (int ni = 0; ni < 2; ++ni)
          acc[mi][ni] = __builtin_amdgcn_mfma_f32_16x16x32_bf16(af[mi], bg[ni], acc[mi][ni], 0, 0, 0);
    }
    __builtin_amdgcn_s_barrier();
  }
  asm volatile("s_waitcnt vmcnt(0)" ::: "memory");

  const int rbase = tm + wm * 32, cbase = tn + wn * 32;
  #pragma unroll
  for (int ni = 0; ni < 2; ++ni) {
    int col = cbase + ni * 16 + l16;
    float bvv = (BIAS && z == 0) ? bias[col] : 0.0f;
    #pragma unroll
    for (int mi = 0; mi < 2; ++mi) {
      #pragma unroll
      for (int rr = 0; rr < 4; ++rr) {
        int row = rbase + mi * 16 + lk * 4 + rr;
        float v = acc[mi][ni][rr] + bvv;
        if (RELU) v = fmaxf(v, 0.0f);
        size_t idx = (size_t)row * N + col;
        if (OF32) Cf[zoff + idx] = v;
        if (OB16) Cb[idx] = f2b(v);
      }
    }
  }
}

// ---------- logits: BM=256 x BN=256, BK=32, 8 waves (2Mx4N), 3-parity ring, lead 2 ----------
// R13 verbatim (best verified: 210us, 0 bank conflicts): 8-quad swizzle write k8=qq^((rr>>1)&3),
// read ch=lk^((row>>1)&3).
__global__ __launch_bounds__(512, 2) void gemm_logits256(
    const unsigned short* __restrict__ A, const unsigned short* __restrict__ E,
    float* __restrict__ Out)
{
  constexpr int NT  = 32;            // K=1024 / BK=32
  constexpr int NWG = 6 * 197;       // M-tiles x N-panels(256)
  __shared__ __align__(16) unsigned short Asl[3][256 * 32];   // 3 x 16KB
  __shared__ __align__(16) unsigned short Bsl[3][256 * 32];   // 3 x 16KB

  const int tid  = threadIdx.x;
  const int lane = tid & 63, wave = tid >> 6;
  const int wm = wave >> 2, wn = wave & 3;       // 2M x 4N, per-wave 128x64
  const int l16 = lane & 15, lk = lane >> 4;

  // bijective XCD swizzle (m204): 1182 = 8*147 + 6
  int orig = blockIdx.x;
  int xcd = orig & 7, local = orig >> 3;
  constexpr int q = NWG / 8, r8 = NWG % 8;
  int wgid = (xcd < r8 ? xcd * (q + 1) : r8 * (q + 1) + (xcd - r8) * q) + local;
  const int tm = (wgid % 6) * 256;   // 6 consecutive wgid share the same B panel
  const int tn = (wgid / 6) * 256;

  f32x4 acc[8][4] = {};

  auto stageA = [&](int t, int s) {
    #pragma unroll
    for (int i = 0; i < 2; ++i) {                 // 1024 chunks = 16KB
      int c = i * 512 + tid;
      int rr = c >> 2, qq = c & 3;
      int k8 = qq ^ ((rr >> 1) & 3);              // 8-quad involution
      gload16(A + (size_t)(tm + rr) * 1024 + t * 32 + k8 * 8, &Asl[s][c * 8]);
    }
  };
  auto stageB = [&](int t, int s) {
    #pragma unroll
    for (int i = 0; i < 2; ++i) {                 // 1024 chunks = 16KB
      int c = i * 512 + tid;
      int rr = c >> 2, qq = c & 3;
      int k8 = qq ^ ((rr >> 1) & 3);
      int row = tn + rr; if (row > V - 1) row = V - 1;   // clamp OOB vocab rows
      gload16(E + (size_t)row * 1024 + t * 32 + k8 * 8, &Bsl[s][c * 8]);
    }
  };

  // prologue: steps 0,1 fully in flight (8 instr/wave)
  stageA(0, 0); stageB(0, 0);
  stageA(1, 1); stageB(1, 1);

  for (int t = 0; t < NT; ++t) {
    const int s  = t % 3;
    const int t2 = (t + 2 < NT) ? t + 2 : NT - 1;   // dummy tail keeps vmcnt uniform
    const int s2 = (t + 2) % 3;                     // distinct from s and (t+1)%3
    asm volatile("s_waitcnt vmcnt(4)" ::: "memory"); // step-t landed (t+1's 4 in flight)
    __builtin_amdgcn_s_barrier();                    // step-t chunks visible to all waves
    const unsigned short* as = &Asl[s][0];
    const unsigned short* bs = &Bsl[s][0];
    bf16x8 af[8], bg[4];
    #pragma unroll
    for (int mi = 0; mi < 8; ++mi) {
      int row = wm * 128 + mi * 16 + l16;
      int ch = lk ^ ((row >> 1) & 3);
      af[mi] = *(const bf16x8*)(as + row * 32 + ch * 8);
    }
    #pragma unroll
    for (int ni = 0; ni < 4; ++ni) {
      int row = wn * 64 + ni * 16 + l16;
      int ch = lk ^ ((row >> 1) & 3);
      bg[ni] = *(const bf16x8*)(bs + row * 32 + ch * 8);
    }
    stageA(t2, s2); stageB(t2, s2);                  // 4 instr; lead = 2 steps
    __builtin_amdgcn_s_setprio(1);
    #pragma unroll
    for (int mi = 0; mi < 8; ++mi)
      #pragma unroll
      for (int ni = 0; ni < 4; ++ni)
        acc[mi][ni] = __builtin_amdgcn_mfma_f32_16x16x32_bf16(af[mi], bg[ni], acc[mi][ni], 0, 0, 0);
    __builtin_amdgcn_s_setprio(0);
  }
  asm volatile("s_waitcnt vmcnt(0)" ::: "memory");   // drain dummies before stores/endpgm

  #pragma unroll
  for (int mi = 0; mi < 8; ++mi) {
    #pragma unroll
    for (int rr = 0; rr < 4; ++rr) {
      int row = tm + wm * 128 + mi * 16 + lk * 4 + rr;  // 0..1535 padded
      int kk = row >> 9, bp = row & 511, b = bp >> 8, p = bp & 255;
      if (p >= PLEN) continue;
      size_t obase = ((size_t)((b * PLEN + p) * KD + kk)) * V;
      #pragma unroll
      for (int ni = 0; ni < 4; ++ni) {
        int col = tn + wn * 64 + ni * 16 + l16;
        if (col < V) Out[obase + col] = acc[mi][ni][rr];
      }
    }
  }
}

extern "C" void kernel_launch(void* const* d_in, const int* in_sizes, int n_in,
                              void* d_out, int out_size, void* d_ws, size_t ws_size,
                              hipStream_t stream)
{
  (void)in_sizes; (void)n_in; (void)out_size; (void)ws_size;
  const float* x      = (const float*)d_in[0];
  const float* embedw = (const float*)d_in[1];
  const float* rmsw   = (const float*)d_in[2];
  const float* projw  = (const float*)d_in[3];
  const float* projb  = (const float*)d_in[4];
  const float* ainw   = (const float*)d_in[5];
  const float* ainb   = (const float*)d_in[6];
  const float* aoutw  = (const float*)d_in[7];
  const float* aoutb  = (const float*)d_in[8];
  const float* ff1w   = (const float*)d_in[9];
  const float* ff1b   = (const float*)d_in[10];
  const float* ff2w   = (const float*)d_in[11];
  const float* ff2b   = (const float*)d_in[12];
  const float* ln1w   = (const float*)d_in[13];
  const float* ln1b   = (const float*)d_in[14];
  const float* ln2w   = (const float*)d_in[15];
  const float* ln2b   = (const float*)d_in[16];
  float* out = (float*)d_out;

  char* ws = (char*)d_ws;
  size_t off = 0;
  auto alloc = [&](size_t bytes) -> void* {
    void* ptr = ws + off;
    off = (off + bytes + 255) & ~(size_t)255;
    return ptr;
  };
  unsigned short* embed_b = (unsigned short*)alloc((size_t)V * D * 2);
  unsigned short* projw_b = (unsigned short*)alloc((size_t)KD * D * 2 * D * 2);
  unsigned short* ainw_b  = (unsigned short*)alloc((size_t)KD * D * D * 2);   // V-slice only
  unsigned short* aoutw_b = (unsigned short*)alloc((size_t)KD * D * D * 2);
  unsigned short* ff1w_b  = (unsigned short*)alloc((size_t)KD * DFF * D * 2);
  unsigned short* ff2w_b  = (unsigned short*)alloc((size_t)KD * D * DFF * 2);
  unsigned short* h_all   = (unsigned short*)alloc((size_t)KD * MR * D * 2);
  unsigned short* merged  = (unsigned short*)alloc((size_t)MR * 2 * D * 2);
  float*          pp      = (float*)alloc((size_t)2 * MR * D * 4);   // proj/v split-K partials
  float*          p_f     = (float*)alloc((size_t)MR * D * 4);
  unsigned short* p_b     = (unsigned short*)alloc((size_t)MR * D * 2);
  unsigned short* v_b     = (unsigned short*)alloc((size_t)MR * D * 2);
  float*          sa_f    = (float*)alloc((size_t)2 * MR * D * 4);   // split-K partials
  float*          s1_f    = (float*)alloc((size_t)MR * D * 4);
  unsigned short* s1_b    = (unsigned short*)alloc((size_t)MR * D * 2);
  unsigned short* ff_b    = (unsigned short*)alloc((size_t)MR * DFF * 2);
  float*          ff2_f   = (float*)alloc((size_t)2 * MR * D * 4);   // split-K partials

  // weight converts: embed split 4 ways so all slices finish together
  const long EQ = ((long)V * D) / 4;
  cvt_all<<<dim3(768, 6), dim3(256), 0, stream>>>(
      embedw + 0 * EQ, embed_b + 0 * EQ, EQ,
      embedw + 1 * EQ, embed_b + 1 * EQ, EQ,
      embedw + 2 * EQ, embed_b + 2 * EQ, EQ,
      embedw + 3 * EQ, embed_b + 3 * EQ, (long)V * D - 3 * EQ,
      projw,  projw_b, (long)KD * D * 2 * D,
      ff1w,   ff1w_b,  (long)KD * DFF * D);
  cvt_all<<<dim3(512, 6), dim3(256), 0, stream>>>(
      ainw + (size_t)0 * 3 * D * D + 2 * D * D, ainw_b + (size_t)0 * D * D, (long)D * D,
      ainw + (size_t)1 * 3 * D * D + 2 * D * D, ainw_b + (size_t)1 * D * D, (long)D * D,
      ainw + (size_t)2 * 3 * D * D + 2 * D * D, ainw_b + (size_t)2 * D * D, (long)D * D,
      aoutw,  aoutw_b, (long)KD * D * D,
      ff2w,   ff2w_b,  (long)KD * D * DFF,
      (const float*)nullptr, (unsigned short*)nullptr, 0);

  rms_merge<<<dim3(MR), dim3(256), 0, stream>>>(x, x, rmsw, merged, 0);

  for (int k = 0; k < KD; ++k) {
    // p = merged @ proj_w[k]^T + proj_b[k]   (K=2048) -- split-K=2 -> pp; reduce -> p_f,p_b
    gemm2<true,false,true,false,2><<<dim3(D/64, MR/64, 2), dim3(256), 0, stream>>>(
        merged, projw_b + (size_t)k * D * 2 * D, projb + (size_t)k * D, pp, (unsigned short*)nullptr, D, 2 * D);
    red_pv<true><<<dim3(MR), dim3(256), 0, stream>>>(pp, p_f, p_b);
    // v = p @ wv^T + bv   (K=1024) -- split-K=2 -> pp; reduce -> v_b
    gemm2<true,false,true,false,2><<<dim3(D/64, MR/64, 2), dim3(256), 0, stream>>>(
        p_b, ainw_b + (size_t)k * D * D, ainb + (size_t)k * 3 * D + 2 * D, pp, (unsigned short*)nullptr, D, D);
    red_pv<false><<<dim3(MR), dim3(256), 0, stream>>>(pp, (float*)nullptr, v_b);
    // sa = v @ attn_out_w[k]^T + b -- split-K=2, partials summed by add_ln3
    gemm2<true,false,true,false,2><<<dim3(D/64, MR/64, 2), dim3(256), 0, stream>>>(
        v_b, aoutw_b + (size_t)k * D * D, aoutb + (size_t)k * D, sa_f, (unsigned short*)nullptr, D, D);
    // s1 = LN(p + sa0 + sa1)
    add_ln3<<<dim3(MR), dim3(256), 0, stream>>>(
        p_f, sa_f, sa_f + (size_t)MR * D, ln1w + (size_t)k * D, ln1b + (size_t)k * D, s1_f, s1_b);
    // ff = relu(s1 @ ff1_w[k]^T + b)   (N=2048, grid 256 already full)
    gemm2<true,true,false,true,1><<<dim3(DFF/64, MR/64), dim3(256), 0, stream>>>(
        s1_b, ff1w_b + (size_t)k * DFF * D, ff1b + (size_t)k * DFF, (float*)nullptr, ff_b, DFF, D);
    // ff2 = ff @ ff2_w[k]^T + b   (K=2048) -- split-K=2, partials summed by add_ln_rms3
    gemm2<true,false,true,false,2><<<dim3(D/64, MR/64, 2), dim3(256), 0, stream>>>(
        ff_b, ff2w_b + (size_t)k * D * DFF, ff2b + (size_t)k * D, ff2_f, (unsigned short*)nullptr, D, 2 * D);
    // h = LN(s1 + ff2a + ff2b) -> h_all[k]; for k<2 also merged for depth k+1
    if (k < KD - 1)
      add_ln_rms3<true><<<dim3(MR), dim3(256), 0, stream>>>(
          s1_f, ff2_f, ff2_f + (size_t)MR * D, ln2w + (size_t)k * D, ln2b + (size_t)k * D, rmsw, x,
          h_all + (size_t)k * MR * D, merged, k + 1);
    else
      add_ln_rms3<false><<<dim3(MR), dim3(256), 0, stream>>>(
          s1_f, ff2_f, ff2_f + (size_t)MR * D, ln2w + (size_t)k * D, ln2b + (size_t)k * D, rmsw, x,
          h_all + (size_t)k * MR * D, (unsigned short*)nullptr, 0);
  }

  // logits: (1536 x 1024) @ (50257 x 1024)^T, 256^2 3-parity deep pipeline (fixed swizzle)
  gemm_logits256<<<dim3(6 * 197), dim3(512), 0, stream>>>(h_all, embed_b, out);
}